// Round 1
// baseline (170.401 us; speedup 1.0000x reference)
//
#include <hip/hip_runtime.h>
#include <math.h>

#define B_DIM 1024
#define D_DIM 512
#define H_DIM 128
#define S_DIM 511
#define PI_F 3.14159265358979323846f

typedef __attribute__((ext_vector_type(8))) short short8;
typedef __attribute__((ext_vector_type(4))) float f32x4;

static __device__ __forceinline__ unsigned short f2bf(float f) {
    unsigned int u = __float_as_uint(f);
    u += 0x7FFFu + ((u >> 16) & 1u);
    return (unsigned short)(u >> 16);
}

// XOR swizzle for the 128-row x 128B bf16 tiles (A and Bt).
// row stride 128B; spreads bank usage for both stride-1 and stride-4 row access.
__device__ __forceinline__ int swz(int row, int byte_in_row) {
    return (row << 7) + (byte_in_row ^ (((row ^ (row >> 3)) & 7) << 4));
}

__global__ __launch_bounds__(256) void ar_site_kernel(
        const float* __restrict__ z, const float* __restrict__ W1,
        const float* __restrict__ b1, const float* __restrict__ W2,
        const float* __restrict__ b2, float* __restrict__ x_out,
        float* __restrict__ ld_part, float* __restrict__ ld_out, int use_ws)
{
    __shared__ __align__(16) unsigned char lds[32768];  // A: [0,16K), Bt: [16K,32K); reused for p-partials

    const int flat = blockIdx.x;
    const int s    = S_DIM - 1 - (flat >> 3);   // descending K: long blocks first
    const int bblk = flat & 7;
    const int brow0 = bblk * 128;
    const int K    = s + 1;                     // valid K (mask: cols 0..s)
    const int idx  = s + 1;                     // transformed column
    const int tid  = threadIdx.x;
    const int lane = tid & 63;
    const int wid  = tid >> 6;
    const int wr   = wid >> 1;                  // wave row (0..1): rows wr*64..+63
    const int wc   = wid & 1;                   // wave col (0..1): cols wc*64..+63
    const int l15  = lane & 15;
    const int l16  = lane >> 4;

    const float* __restrict__ W1s = W1 + (size_t)s * (D_DIM * H_DIM);

    f32x4 acc[4][4];
#pragma unroll
    for (int mi = 0; mi < 4; ++mi)
#pragma unroll
        for (int ni = 0; ni < 4; ++ni)
            acc[mi][ni] = (f32x4){0.f, 0.f, 0.f, 0.f};

    const int ntiles = (K + 63) >> 6;
    for (int kk = 0; kk < ntiles; ++kk) {
        const int k0 = kk << 6;

        // ---- stage A: z rows [brow0,brow0+128), cols [k0,k0+64), f32 -> bf16, masked at K
        {
            const int colg  = tid & 15;       // 16 col-groups of 4 floats (coalesced)
            const int rbase = tid >> 4;       // 16 rows per pass
            const int kc    = k0 + colg * 4;
            const int rem   = K - kc;         // valid floats among my 4
#pragma unroll
            for (int p = 0; p < 8; ++p) {
                const int row = p * 16 + rbase;
                const float* zp = z + (size_t)(brow0 + row) * D_DIM + kc;
                float4 v = *(const float4*)zp;
                if (rem < 4) {
                    v.x = (0 < rem) ? v.x : 0.f;
                    v.y = (1 < rem) ? v.y : 0.f;
                    v.z = (2 < rem) ? v.z : 0.f;
                    v.w = (3 < rem) ? v.w : 0.f;
                }
                uint2 w;
                w.x = (unsigned)f2bf(v.x) | ((unsigned)f2bf(v.y) << 16);
                w.y = (unsigned)f2bf(v.z) | ((unsigned)f2bf(v.w) << 16);
                *(uint2*)(lds + swz(row, colg * 8)) = w;
            }
        }

        // ---- stage Bt: W1[s] rows [k0,k0+64), all 128 h-cols, transposed to [h][k] bf16
        {
            const int hgrp = tid & 31;        // h cols hgrp*4..+3 (coalesced within a k-row)
            const int kgrp = tid >> 5;        // k rows k0+kgrp*8..+7
            const float* wp = W1s + (size_t)(k0 + kgrp * 8) * H_DIM + hgrp * 4;
            float4 c[8];
#pragma unroll
            for (int j = 0; j < 8; ++j)
                c[j] = *(const float4*)(wp + (size_t)j * H_DIM);
            const float* cf = (const float*)c;
#pragma unroll
            for (int i = 0; i < 4; ++i) {
                uint4 w;
                w.x = (unsigned)f2bf(cf[0 * 4 + i]) | ((unsigned)f2bf(cf[1 * 4 + i]) << 16);
                w.y = (unsigned)f2bf(cf[2 * 4 + i]) | ((unsigned)f2bf(cf[3 * 4 + i]) << 16);
                w.z = (unsigned)f2bf(cf[4 * 4 + i]) | ((unsigned)f2bf(cf[5 * 4 + i]) << 16);
                w.w = (unsigned)f2bf(cf[6 * 4 + i]) | ((unsigned)f2bf(cf[7 * 4 + i]) << 16);
                *(uint4*)(lds + 16384 + swz(hgrp * 4 + i, kgrp * 16)) = w;
            }
        }

        __syncthreads();

        // ---- MFMA: 2 k-steps of 32
#pragma unroll
        for (int ks = 0; ks < 2; ++ks) {
            const int kb = ks * 64 + l16 * 16;   // byte offset along K within row
            short8 af[4], bfr[4];
#pragma unroll
            for (int mi = 0; mi < 4; ++mi)
                af[mi] = *(const short8*)(lds + swz(wr * 64 + mi * 16 + l15, kb));
#pragma unroll
            for (int ni = 0; ni < 4; ++ni)
                bfr[ni] = *(const short8*)(lds + 16384 + swz(wc * 64 + ni * 16 + l15, kb));
#pragma unroll
            for (int mi = 0; mi < 4; ++mi)
#pragma unroll
                for (int ni = 0; ni < 4; ++ni)
                    acc[mi][ni] = __builtin_amdgcn_mfma_f32_16x16x32_bf16(
                        af[mi], bfr[ni], acc[mi][ni], 0, 0, 0);
        }
        __syncthreads();
    }

    // ---- epilogue: h = relu(acc + b1); per-lane partials of p = h @ W2
    float b1v[4], w2a[4], w2b[4];
#pragma unroll
    for (int ni = 0; ni < 4; ++ni) {
        const int c = wc * 64 + ni * 16 + l15;
        b1v[ni] = b1[(size_t)s * H_DIM + c];
        const float* w2p = W2 + ((size_t)s * H_DIM + c) * 2;
        w2a[ni] = w2p[0];
        w2b[ni] = w2p[1];
    }
    // p-partial LDS layout: byte = row*256 + ((wc*128 + j*64 + l15*4) ^ ((row&15)<<4))
#pragma unroll
    for (int mi = 0; mi < 4; ++mi) {
#pragma unroll
        for (int r = 0; r < 4; ++r) {
            float p0 = 0.f, p1 = 0.f;
#pragma unroll
            for (int ni = 0; ni < 4; ++ni) {
                float h = acc[mi][ni][r] + b1v[ni];
                h = fmaxf(h, 0.f);
                p0 = fmaf(h, w2a[ni], p0);
                p1 = fmaf(h, w2b[ni], p1);
            }
            const int row = wr * 64 + mi * 16 + l16 * 4 + r;
            const int sw  = (row & 15) << 4;
            *(float*)(lds + row * 256 + ((wc * 128 + l15 * 4) ^ sw))      = p0;
            *(float*)(lds + row * 256 + ((wc * 128 + 64 + l15 * 4) ^ sw)) = p1;
        }
    }
    __syncthreads();

    // ---- reduce partials, NCP transform, write x column + ld partial
    if (tid < 128) {
        const int row = tid;
        const int sw  = (row & 15) << 4;
        float asum = 0.f, bsum = 0.f;
#pragma unroll
        for (int wcb = 0; wcb < 2; ++wcb) {
#pragma unroll
            for (int q = 0; q < 4; ++q) {
                f32x4 va = *(const f32x4*)(lds + row * 256 + ((wcb * 128 + q * 16) ^ sw));
                f32x4 vb = *(const f32x4*)(lds + row * 256 + ((wcb * 128 + 64 + q * 16) ^ sw));
                asum += va.x + va.y + va.z + va.w;
                bsum += vb.x + vb.y + vb.z + vb.w;
            }
        }
        const int grow = brow0 + row;
        const float alpha = asum + b2[(size_t)s * 2 + 0];
        const float beta  = bsum + b2[(size_t)s * 2 + 1];
        const float phi = z[(size_t)grow * D_DIM + idx];
        const float u = tanf(0.5f * (phi - PI_F));
        const float a = expf(alpha);
        const float v = fmaf(a, u, beta);
        x_out[(size_t)grow * D_DIM + idx] = 2.0f * atanf(v) + PI_F;
        const float ld = alpha + log1pf(u * u) - log1pf(v * v);
        if (use_ws) ld_part[(size_t)s * B_DIM + grow] = ld;
        else        atomicAdd(ld_out + grow, ld);
    }
}

__global__ __launch_bounds__(256) void ar_finalize(
        const float* __restrict__ z, const float* __restrict__ ld_part,
        float* __restrict__ x_out, float* __restrict__ ld_out, int use_ws)
{
    const int b = blockIdx.x * blockDim.x + threadIdx.x;
    if (b >= B_DIM) return;
    x_out[(size_t)b * D_DIM] = z[(size_t)b * D_DIM];   // untouched column 0
    if (use_ws) {
        float acc = 0.f;
        for (int i = 0; i < S_DIM; ++i)
            acc += ld_part[(size_t)i * B_DIM + b];
        ld_out[b] = acc;
    }
}

extern "C" void kernel_launch(void* const* d_in, const int* in_sizes, int n_in,
                              void* d_out, int out_size, void* d_ws, size_t ws_size,
                              hipStream_t stream) {
    const float* z  = (const float*)d_in[0];
    const float* W1 = (const float*)d_in[1];
    const float* b1 = (const float*)d_in[2];
    const float* W2 = (const float*)d_in[3];
    const float* b2 = (const float*)d_in[4];
    float* x_out  = (float*)d_out;
    float* ld_out = x_out + (size_t)B_DIM * D_DIM;

    const size_t need = (size_t)S_DIM * B_DIM * sizeof(float);
    const int use_ws = (ws_size >= need) ? 1 : 0;
    float* ld_part = (float*)d_ws;

    if (!use_ws) {
        hipMemsetAsync(ld_out, 0, B_DIM * sizeof(float), stream);
    }
    ar_site_kernel<<<dim3(S_DIM * 8), dim3(256), 0, stream>>>(
        z, W1, b1, W2, b2, x_out, ld_part, ld_out, use_ws);
    ar_finalize<<<dim3((B_DIM + 255) / 256), dim3(256), 0, stream>>>(
        z, ld_part, x_out, ld_out, use_ws);
}

// Round 2
// 122.574 us; speedup vs baseline: 1.3902x; 1.3902x over previous
//
#include <hip/hip_runtime.h>
#include <math.h>

#define B_DIM 1024
#define D_DIM 512
#define H_DIM 128
#define S_DIM 511
#define PI_F 3.14159265358979323846f
#define ZSWZ_BYTES (8u * 1024u * 128u) /* 8 ktiles x 1024 rows x 128B = 1 MiB */

typedef __attribute__((ext_vector_type(8))) short short8;
typedef __attribute__((ext_vector_type(4))) float f32x4;

static __device__ __forceinline__ unsigned cvt_pk_bf16(float lo, float hi) {
    unsigned r;
    asm("v_cvt_pk_bf16_f32 %0, %1, %2" : "=v"(r) : "v"(lo), "v"(hi));
    return r;
}

// Pre-pass: z (f32, [1024][512]) -> bf16 tiles, XOR-swizzle baked into the
// GLOBAL layout so the main kernel can global_load_lds linearly (m173 pattern).
// Layout: [ktile 0..7][row 0..1023][128 bytes], where within a row the 16B
// group at byte g*16 holds source cols (ktile*64 + (g^(row&7))*8 .. +8).
__global__ __launch_bounds__(256) void z_pack_kernel(
        const float* __restrict__ z, unsigned char* __restrict__ z_swz)
{
    const int gid = blockIdx.x * 256 + threadIdx.x;   // 65536 threads
    const int g   = gid & 7;
    const int row = (gid >> 3) & 1023;
    const int kt  = gid >> 13;
    const int srcg = g ^ (row & 7);
    const float* src = z + (size_t)row * D_DIM + kt * 64 + srcg * 8;
    float4 a = *(const float4*)src;
    float4 b = *(const float4*)(src + 4);
    uint4 w;
    w.x = cvt_pk_bf16(a.x, a.y);
    w.y = cvt_pk_bf16(a.z, a.w);
    w.z = cvt_pk_bf16(b.x, b.y);
    w.w = cvt_pk_bf16(b.z, b.w);
    *(uint4*)(z_swz + (size_t)kt * 131072 + row * 128 + g * 16) = w;
}

template<bool PRE>
__global__ __launch_bounds__(256) void ar_site_kernel(
        const float* __restrict__ z, const unsigned char* __restrict__ z_swz,
        const float* __restrict__ W1, const float* __restrict__ b1,
        const float* __restrict__ W2, const float* __restrict__ b2,
        float* __restrict__ x_out, float* __restrict__ ld_part,
        float* __restrict__ ld_out)
{
    __shared__ __align__(16) unsigned char lds[32768];  // A:[0,16K) Bt:[16K,32K); reused for p-partials

    // XCD grouping: the 8 b-blocks of one site share blockIdx%8 -> same XCD L2.
    const int ib    = blockIdx.x;
    const int s_idx = ((ib >> 6) << 3) | (ib & 7);      // 0..511, ascending = longest-K first
    if (s_idx >= S_DIM) return;
    const int s     = S_DIM - 1 - s_idx;                // descending K
    const int bblk  = (ib >> 3) & 7;
    const int brow0 = bblk * 128;
    const int K     = s + 1;
    const int idx   = s + 1;
    const int tid   = threadIdx.x;
    const int lane  = tid & 63;
    const int wid   = tid >> 6;
    const int wr    = wid >> 1;
    const int wc    = wid & 1;
    const int l15   = lane & 15;
    const int l16   = lane >> 4;

    const float* __restrict__ W1s = W1 + (size_t)s * (D_DIM * H_DIM);

    f32x4 acc[4][4];
#pragma unroll
    for (int mi = 0; mi < 4; ++mi)
#pragma unroll
        for (int ni = 0; ni < 4; ++ni)
            acc[mi][ni] = (f32x4){0.f, 0.f, 0.f, 0.f};

    const int ntiles = (K + 63) >> 6;
    for (int kk = 0; kk < ntiles; ++kk) {
        const int k0 = kk << 6;

        // ---- stage A (z rows, bf16, swizzled)
        if (PRE) {
            const unsigned char* src = z_swz + (size_t)kk * 131072 + (size_t)brow0 * 128
                                       + wid * 4096 + lane * 16;
            unsigned char* dst = lds + wid * 4096;   // wave-uniform base; HW adds lane*16
#pragma unroll
            for (int i2 = 0; i2 < 4; ++i2) {
                __builtin_amdgcn_global_load_lds(
                    (const __attribute__((address_space(1))) unsigned int*)(src + i2 * 1024),
                    (__attribute__((address_space(3))) unsigned int*)(dst + i2 * 1024),
                    16, 0, 0);
            }
        } else {
            const int g  = tid & 7;
            const int rb = tid >> 3;
#pragma unroll
            for (int p = 0; p < 4; ++p) {
                const int row  = p * 32 + rb;
                const int srcg = g ^ (row & 7);
                const float* zp = z + (size_t)(brow0 + row) * D_DIM + k0 + srcg * 8;
                float4 va = *(const float4*)zp;
                float4 vb = *(const float4*)(zp + 4);
                uint4 w;
                w.x = cvt_pk_bf16(va.x, va.y);
                w.y = cvt_pk_bf16(va.z, va.w);
                w.z = cvt_pk_bf16(vb.x, vb.y);
                w.w = cvt_pk_bf16(vb.z, vb.w);
                *(uint4*)(lds + row * 128 + g * 16) = w;
            }
        }

        // ---- stage Bt: W1[s] rows [k0,k0+64) -> [h][k] bf16, masked at K, swizzled
        {
            const int hgrp  = tid & 31;
            const int kgrp  = tid >> 5;
            const int kbase = k0 + kgrp * 8;
            const float* wp = W1s + (size_t)kbase * H_DIM + hgrp * 4;
            float4 c[8];
#pragma unroll
            for (int j = 0; j < 8; ++j) {
                float4 v = *(const float4*)(wp + (size_t)j * H_DIM);
                const bool ok = (kbase + j) < K;
                v.x = ok ? v.x : 0.f;  v.y = ok ? v.y : 0.f;
                v.z = ok ? v.z : 0.f;  v.w = ok ? v.w : 0.f;
                c[j] = v;
            }
            const float* cf = (const float*)c;
#pragma unroll
            for (int i2 = 0; i2 < 4; ++i2) {
                const int h = hgrp * 4 + i2;
                uint4 w;
                w.x = cvt_pk_bf16(cf[0 * 4 + i2], cf[1 * 4 + i2]);
                w.y = cvt_pk_bf16(cf[2 * 4 + i2], cf[3 * 4 + i2]);
                w.z = cvt_pk_bf16(cf[4 * 4 + i2], cf[5 * 4 + i2]);
                w.w = cvt_pk_bf16(cf[6 * 4 + i2], cf[7 * 4 + i2]);
                *(uint4*)(lds + 16384 + h * 128 + ((kgrp * 16) ^ ((h & 7) << 4))) = w;
            }
        }

        __syncthreads();   // compiler drains vmcnt (global_load_lds) + lgkmcnt here

        // ---- MFMA: 2 k-steps of 32
#pragma unroll
        for (int ks = 0; ks < 2; ++ks) {
            const int kb = ks * 64 + l16 * 16;
            short8 af[4], bfr[4];
#pragma unroll
            for (int mi = 0; mi < 4; ++mi) {
                const int r = wr * 64 + mi * 16 + l15;
                af[mi] = *(const short8*)(lds + r * 128 + (kb ^ ((r & 7) << 4)));
            }
#pragma unroll
            for (int ni = 0; ni < 4; ++ni) {
                const int h = wc * 64 + ni * 16 + l15;
                bfr[ni] = *(const short8*)(lds + 16384 + h * 128 + (kb ^ ((h & 7) << 4)));
            }
#pragma unroll
            for (int mi = 0; mi < 4; ++mi)
#pragma unroll
                for (int ni = 0; ni < 4; ++ni)
                    acc[mi][ni] = __builtin_amdgcn_mfma_f32_16x16x32_bf16(
                        af[mi], bfr[ni], acc[mi][ni], 0, 0, 0);
        }
        __syncthreads();
    }

    // ---- epilogue: h = relu(acc + b1); per-lane partials of p = h @ W2
    float b1v[4], w2a[4], w2b[4];
#pragma unroll
    for (int ni = 0; ni < 4; ++ni) {
        const int c = wc * 64 + ni * 16 + l15;
        b1v[ni] = b1[(size_t)s * H_DIM + c];
        const float* w2p = W2 + ((size_t)s * H_DIM + c) * 2;
        w2a[ni] = w2p[0];
        w2b[ni] = w2p[1];
    }
#pragma unroll
    for (int mi = 0; mi < 4; ++mi) {
#pragma unroll
        for (int r = 0; r < 4; ++r) {
            float p0 = 0.f, p1 = 0.f;
#pragma unroll
            for (int ni = 0; ni < 4; ++ni) {
                float h = acc[mi][ni][r] + b1v[ni];
                h = fmaxf(h, 0.f);
                p0 = fmaf(h, w2a[ni], p0);
                p1 = fmaf(h, w2b[ni], p1);
            }
            const int row = wr * 64 + mi * 16 + l16 * 4 + r;
            const int sw  = (row & 15) << 4;
            *(float*)(lds + row * 256 + ((wc * 128 + l15 * 4) ^ sw))      = p0;
            *(float*)(lds + row * 256 + ((wc * 128 + 64 + l15 * 4) ^ sw)) = p1;
        }
    }
    __syncthreads();

    // ---- reduce partials, NCP transform, write x column + ld partial
    if (tid < 128) {
        const int row = tid;
        const int sw  = (row & 15) << 4;
        float asum = 0.f, bsum = 0.f;
#pragma unroll
        for (int wcb = 0; wcb < 2; ++wcb) {
#pragma unroll
            for (int q = 0; q < 4; ++q) {
                f32x4 va = *(const f32x4*)(lds + row * 256 + ((wcb * 128 + q * 16) ^ sw));
                f32x4 vb = *(const f32x4*)(lds + row * 256 + ((wcb * 128 + 64 + q * 16) ^ sw));
                asum += va.x + va.y + va.z + va.w;
                bsum += vb.x + vb.y + vb.z + vb.w;
            }
        }
        const int grow = brow0 + row;
        const float alpha = asum + b2[(size_t)s * 2 + 0];
        const float beta  = bsum + b2[(size_t)s * 2 + 1];
        const float phi = z[(size_t)grow * D_DIM + idx];
        const float u = tanf(0.5f * (phi - PI_F));
        const float a = expf(alpha);
        const float v = fmaf(a, u, beta);
        x_out[(size_t)grow * D_DIM + idx] = 2.0f * atanf(v) + PI_F;
        const float ld = alpha + log1pf(u * u) - log1pf(v * v);
        if (PRE) ld_part[(size_t)s * B_DIM + grow] = ld;
        else     atomicAdd(ld_out + grow, ld);
    }
}

__global__ __launch_bounds__(256) void ar_finalize(
        const float* __restrict__ z, const float* __restrict__ ld_part,
        float* __restrict__ x_out, float* __restrict__ ld_out, int use_ws)
{
    const int b = blockIdx.x * blockDim.x + threadIdx.x;
    if (b >= B_DIM) return;
    x_out[(size_t)b * D_DIM] = z[(size_t)b * D_DIM];   // untouched column 0
    if (use_ws) {
        float acc = 0.f;
        for (int i = 0; i < S_DIM; ++i)
            acc += ld_part[(size_t)i * B_DIM + b];
        ld_out[b] = acc;
    }
}

extern "C" void kernel_launch(void* const* d_in, const int* in_sizes, int n_in,
                              void* d_out, int out_size, void* d_ws, size_t ws_size,
                              hipStream_t stream) {
    const float* z  = (const float*)d_in[0];
    const float* W1 = (const float*)d_in[1];
    const float* b1 = (const float*)d_in[2];
    const float* W2 = (const float*)d_in[3];
    const float* b2 = (const float*)d_in[4];
    float* x_out  = (float*)d_out;
    float* ld_out = x_out + (size_t)B_DIM * D_DIM;

    const size_t need = (size_t)ZSWZ_BYTES + (size_t)S_DIM * B_DIM * sizeof(float);
    unsigned char* z_swz = (unsigned char*)d_ws;
    float* ld_part = (float*)((unsigned char*)d_ws + ZSWZ_BYTES);

    if (ws_size >= need) {
        z_pack_kernel<<<dim3(256), dim3(256), 0, stream>>>(z, z_swz);
        ar_site_kernel<true><<<dim3(4096), dim3(256), 0, stream>>>(
            z, z_swz, W1, b1, W2, b2, x_out, ld_part, ld_out);
        ar_finalize<<<dim3(4), dim3(256), 0, stream>>>(z, ld_part, x_out, ld_out, 1);
    } else {
        hipMemsetAsync(ld_out, 0, B_DIM * sizeof(float), stream);
        ar_site_kernel<false><<<dim3(4096), dim3(256), 0, stream>>>(
            z, nullptr, W1, b1, W2, b2, x_out, nullptr, ld_out);
        ar_finalize<<<dim3(4), dim3(256), 0, stream>>>(z, nullptr, x_out, ld_out, 0);
    }
}